// Round 3
// baseline (448.766 us; speedup 1.0000x reference)
//
#include <hip/hip_runtime.h>

#define K_DIM 4096
#define N_DIM 8192   // rows of x
#define M_DIM 4096   // rows of weight

typedef int v4i __attribute__((ext_vector_type(4)));
typedef int v16i __attribute__((ext_vector_type(16)));

// ---------------- fused amax over x and w (ILP-4) ----------------
// blocks [0,2048) reduce x -> scal[0]; blocks [2048,3072) reduce w -> scal[1]
__global__ void amax2_kernel(const float4* __restrict__ x,
                             const float4* __restrict__ w,
                             unsigned* __restrict__ scal) {
  const int XB = 2048, WB = 1024;
  const float4* p;
  int n4, b, nb;
  unsigned* out;
  if (blockIdx.x < XB) {
    p = x; n4 = N_DIM * K_DIM / 4; out = scal + 0; b = blockIdx.x; nb = XB;
  } else {
    p = w; n4 = M_DIM * K_DIM / 4; out = scal + 1; b = blockIdx.x - XB; nb = WB;
  }
  const int stride = nb * blockDim.x;
  int i = b * blockDim.x + threadIdx.x;
  float m = 0.f;
  // main: 4 independent loads in flight (n4 = 16*stride for both regions)
  for (; i + 3 * stride < n4; i += 4 * stride) {
    float4 v0 = p[i];
    float4 v1 = p[i + stride];
    float4 v2 = p[i + 2 * stride];
    float4 v3 = p[i + 3 * stride];
    float m0 = fmaxf(fmaxf(fabsf(v0.x), fabsf(v0.y)),
                     fmaxf(fabsf(v0.z), fabsf(v0.w)));
    float m1 = fmaxf(fmaxf(fabsf(v1.x), fabsf(v1.y)),
                     fmaxf(fabsf(v1.z), fabsf(v1.w)));
    float m2 = fmaxf(fmaxf(fabsf(v2.x), fabsf(v2.y)),
                     fmaxf(fabsf(v2.z), fabsf(v2.w)));
    float m3 = fmaxf(fmaxf(fabsf(v3.x), fabsf(v3.y)),
                     fmaxf(fabsf(v3.z), fabsf(v3.w)));
    m = fmaxf(m, fmaxf(fmaxf(m0, m1), fmaxf(m2, m3)));
  }
  for (; i < n4; i += stride) {  // tail (empty for these sizes)
    float4 v = p[i];
    m = fmaxf(m, fmaxf(fmaxf(fabsf(v.x), fabsf(v.y)),
                       fmaxf(fabsf(v.z), fabsf(v.w))));
  }
#pragma unroll
  for (int off = 32; off > 0; off >>= 1)
    m = fmaxf(m, __shfl_down(m, off));
  __shared__ float sm[4];
  int lane = threadIdx.x & 63, wv = threadIdx.x >> 6;
  if (lane == 0) sm[wv] = m;
  __syncthreads();
  if (threadIdx.x == 0) {
    m = fmaxf(fmaxf(sm[0], sm[1]), fmaxf(sm[2], sm[3]));
    atomicMax(out, __float_as_uint(m));  // values >= 0: uint order == float order
  }
}

// ---------------- fused quantize fp32 -> int8 (ILP-4, coalesced R+W) -------
__device__ __forceinline__ unsigned pack4(float4 v, float s) {
  int q0 = (int)fminf(fmaxf(rintf(v.x * s), -127.f), 127.f);
  int q1 = (int)fminf(fmaxf(rintf(v.y * s), -127.f), 127.f);
  int q2 = (int)fminf(fmaxf(rintf(v.z * s), -127.f), 127.f);
  int q3 = (int)fminf(fmaxf(rintf(v.w * s), -127.f), 127.f);
  return (unsigned)(q0 & 255) | ((unsigned)(q1 & 255) << 8) |
         ((unsigned)(q2 & 255) << 16) | ((unsigned)(q3 & 255) << 24);
}

__global__ void quant2_kernel(const float4* __restrict__ x,
                              const float4* __restrict__ w,
                              unsigned* __restrict__ qx,
                              unsigned* __restrict__ qw,
                              const unsigned* __restrict__ scal) {
  const int XB = 2048, WB = 1024;
  const float4* in;
  unsigned* out;
  int n4, b, nb;
  float amax;
  if (blockIdx.x < XB) {
    in = x; out = qx; n4 = N_DIM * K_DIM / 4; b = blockIdx.x; nb = XB;
    amax = __uint_as_float(scal[0]);
  } else {
    in = w; out = qw; n4 = M_DIM * K_DIM / 4; b = blockIdx.x - XB; nb = WB;
    amax = __uint_as_float(scal[1]);
  }
  const float s = 127.0f / amax;
  const int stride = nb * blockDim.x;
  int i = b * blockDim.x + threadIdx.x;
  for (; i + 3 * stride < n4; i += 4 * stride) {
    float4 v0 = in[i];
    float4 v1 = in[i + stride];
    float4 v2 = in[i + 2 * stride];
    float4 v3 = in[i + 3 * stride];
    out[i] = pack4(v0, s);
    out[i + stride] = pack4(v1, s);
    out[i + 2 * stride] = pack4(v2, s);
    out[i + 3 * stride] = pack4(v3, s);
  }
  for (; i < n4; i += stride) out[i] = pack4(in[i], s);  // tail (empty here)
}

// ---------------- int8 GEMM: out = qx (N,K) * qw^T (K,M), dequant + bias ----
__device__ __forceinline__ void gld_lds16(const void* g, void* l) {
  __builtin_amdgcn_global_load_lds(
      (const __attribute__((address_space(1))) void*)g,
      (__attribute__((address_space(3))) void*)l, 16, 0, 0);
}

// 128x128 tile, BK=128, XOR-swizzled LDS, 32x32x32 i8 MFMA, 2x2 tiles/wave
__global__ __launch_bounds__(256, 2) void gemm_i8(
    const signed char* __restrict__ A,   // qx  [N_DIM][K_DIM]
    const signed char* __restrict__ B,   // qw  [M_DIM][K_DIM]
    const float* __restrict__ bias,      // [M_DIM]
    float* __restrict__ out,             // [N_DIM][M_DIM]
    const unsigned* __restrict__ scal)   // [0]=amax_x bits [1]=amax_w bits
{
  __shared__ signed char la[128 * 128];  // 16 KB  A-tile [128 rows][128 k-bytes]
  __shared__ signed char lb[128 * 128];  // 16 KB  B-tile

  const int tid = threadIdx.x;
  const int lane = tid & 63;
  const int w = tid >> 6;          // wave 0..3, arranged 2x2 over 128x128
  const int wr = (w & 1) * 64;     // wave row offset (A/x dim)
  const int wc = (w >> 1) * 64;    // wave col offset (B/w dim)
  const long r0 = (long)blockIdx.x * 128;
  const long c0 = (long)blockIdx.y * 128;

  // staging: per pass p (0..3): row = p*32 + (tid>>3), LDS chunk = tid&7,
  // which must hold global chunk (tid&7) ^ (row&7); row&7 == (tid>>3)&7.
  const int srow = tid >> 3;                       // 0..31
  const int gcol = ((tid & 7) ^ (srow & 7)) * 16;  // swizzled source column
  const signed char* ga = A + (r0 + srow) * K_DIM + gcol;
  const signed char* gb = B + (c0 + srow) * K_DIM + gcol;

  v16i acc[2][2];
#pragma unroll
  for (int i = 0; i < 2; ++i)
#pragma unroll
    for (int j = 0; j < 2; ++j)
#pragma unroll
      for (int t = 0; t < 16; ++t) acc[i][j][t] = 0;

  const int ln = lane & 31;   // fragment row/col within 32x32
  const int hk = lane >> 5;   // half-k selector: k = hk*16 + j (16 bytes/lane)
  const int sa = ln & 7;      // swizzle key for fragment reads

  for (int k0 = 0; k0 < K_DIM; k0 += 128) {
#pragma unroll
    for (int p = 0; p < 4; ++p) {
      gld_lds16(ga + (long)p * 32 * K_DIM + k0, la + p * 4096 + tid * 16);
      gld_lds16(gb + (long)p * 32 * K_DIM + k0, lb + p * 4096 + tid * 16);
    }
    __syncthreads();  // drains vmcnt (global_load_lds) + barrier

#pragma unroll
    for (int ks = 0; ks < 4; ++ks) {   // K=32 per MFMA
      const int ck = ks * 2 + hk;      // 16B chunk index within 128B row
      v4i av[2], bv[2];
#pragma unroll
      for (int i = 0; i < 2; ++i)
        av[i] = *(const v4i*)(la + (wr + i * 32 + ln) * 128 + ((ck ^ sa) * 16));
#pragma unroll
      for (int j = 0; j < 2; ++j)
        bv[j] = *(const v4i*)(lb + (wc + j * 32 + ln) * 128 + ((ck ^ sa) * 16));
#pragma unroll
      for (int i = 0; i < 2; ++i)
#pragma unroll
        for (int j = 0; j < 2; ++j)
          acc[i][j] = __builtin_amdgcn_mfma_i32_32x32x32_i8(av[i], bv[j],
                                                            acc[i][j], 0, 0, 0);
    }
    __syncthreads();  // protect LDS before next stage
  }

  const float dq =
      (__uint_as_float(scal[0]) * __uint_as_float(scal[1])) / 16129.0f;
  float bs[2];
#pragma unroll
  for (int j = 0; j < 2; ++j) bs[j] = bias[c0 + wc + j * 32 + ln];

  // C/D 32x32 layout: col = lane&31, row = (reg&3) + 8*(reg>>2) + 4*(lane>>5)
#pragma unroll
  for (int i = 0; i < 2; ++i) {
#pragma unroll
    for (int j = 0; j < 2; ++j) {
      const long c = c0 + wc + j * 32 + ln;
#pragma unroll
      for (int reg = 0; reg < 16; ++reg) {
        const long r = r0 + wr + i * 32 + (reg & 3) + 8 * (reg >> 2) + 4 * hk;
        out[r * (long)M_DIM + c] = (float)acc[i][j][reg] * dq + bs[j];
      }
    }
  }
}

extern "C" void kernel_launch(void* const* d_in, const int* in_sizes, int n_in,
                              void* d_out, int out_size, void* d_ws, size_t ws_size,
                              hipStream_t stream) {
  const float* x = (const float*)d_in[0];      // [8192,4096]
  const float* wt = (const float*)d_in[1];     // [4096,4096]
  const float* bias = (const float*)d_in[2];   // [4096]
  float* out = (float*)d_out;

  unsigned* scal = (unsigned*)d_ws;                       // 2 scalars
  signed char* qx = (signed char*)d_ws + 256;             // 32 MiB
  signed char* qw = qx + (long)N_DIM * K_DIM;             // 16 MiB

  hipMemsetAsync(d_ws, 0, 16, stream);  // zero amax slots (ws poisoned 0xAA)

  amax2_kernel<<<3072, 256, 0, stream>>>((const float4*)x, (const float4*)wt,
                                         scal);
  quant2_kernel<<<3072, 256, 0, stream>>>((const float4*)x, (const float4*)wt,
                                          (unsigned*)qx, (unsigned*)qw, scal);

  dim3 grid(N_DIM / 128, M_DIM / 128);  // 64 x 32
  gemm_i8<<<grid, 256, 0, stream>>>(qx, qw, bias, out, scal);
}